// Round 8
// baseline (630.147 us; speedup 1.0000x reference)
//
#include <hip/hip_runtime.h>

#define CH 64
#define CHUNK 4096
#define BSHIFT 8          // 256 nodes per bucket
#define NBUCK 196         // ceil(50000 / 256); requires N < 65536 (16-bit packing)

__device__ __forceinline__ unsigned short f2bf_rne(float f) {
    unsigned int u = __float_as_uint(f);
    u += 0x7fffu + ((u >> 16) & 1u);   // round to nearest even
    return (unsigned short)(u >> 16);
}
__device__ __forceinline__ float bf_lo(unsigned int q) {
    return __uint_as_float(q << 16);
}
__device__ __forceinline__ float bf_hi(unsigned int q) {
    return __uint_as_float(q & 0xffff0000u);
}
__device__ __forceinline__ unsigned int pack2bf(float lo, float hi) {
    return (unsigned int)f2bf_rne(lo) | ((unsigned int)f2bf_rne(hi) << 16);
}

// ---------- pass 1: per-chunk bucket histogram (non-atomic global write) ----------
__global__ __launch_bounds__(256) void bucket_hist_kernel(
        const int* __restrict__ dst, int* __restrict__ chunk_hist, int E) {
    __shared__ int hist[256];
    int tid = threadIdx.x;
    int e0 = blockIdx.x * CHUNK;
    int total = min(CHUNK, E - e0);
    hist[tid] = 0;
    __syncthreads();
    for (int i = tid; i < total; i += 256)
        atomicAdd(&hist[dst[e0 + i] >> BSHIFT], 1);
    __syncthreads();
    if (tid < NBUCK) chunk_hist[blockIdx.x * NBUCK + tid] = hist[tid];
}

// ---------- pass 2: column-scan chunk hists -> per-chunk bases; block 1: gptr ----------
__global__ __launch_bounds__(256) void scan_gptr_kernel(
        const int* __restrict__ chunk_hist, int cb,
        int* __restrict__ chunk_base, int* __restrict__ bucket_base,
        int* __restrict__ rowptr,
        const int* __restrict__ batch, int* __restrict__ gptr,
        int N, int E, int NG) {
    if (blockIdx.x == 0) {
        __shared__ int sc[256];
        int t = threadIdx.x;
        int total = 0;
        if (t < NBUCK)
            for (int c = 0; c < cb; ++c) total += chunk_hist[c * NBUCK + t];
        sc[t] = total;
        __syncthreads();
        for (int off = 1; off < 256; off <<= 1) {
            int v = (t >= off) ? sc[t - off] : 0;
            __syncthreads();
            sc[t] += v;
            __syncthreads();
        }
        int base = sc[t] - total;   // exclusive prefix over buckets
        if (t < NBUCK) {
            bucket_base[t] = base;
            int run = base;
            for (int c = 0; c < cb; ++c) {
                chunk_base[c * NBUCK + t] = run;
                run += chunk_hist[c * NBUCK + t];
            }
        }
        if (t == NBUCK - 1) bucket_base[NBUCK] = sc[t];
        if (t == 0) rowptr[N] = E;
    } else {
        // graph boundaries by binary search (batch sorted)
        for (int g = threadIdx.x; g <= NG; g += 256) {
            if (g == NG) { gptr[NG] = N; continue; }
            int lo = 0, hi = N;
            while (lo < hi) {
                int mid = (lo + hi) >> 1;
                if (batch[mid] < g) lo = mid + 1; else hi = mid;
            }
            gptr[g] = lo;
        }
    }
}

// ---------- pass 3: bin edges into bucket regions (no global atomics) ----------
// pairs packed as (dst<<16)|src  (N < 65536)
__global__ __launch_bounds__(256) void bin_kernel(
        const int* __restrict__ src, const int* __restrict__ dst,
        const int* __restrict__ chunk_base, unsigned int* __restrict__ pairs, int E) {
    __shared__ unsigned int stage[CHUNK];                 // 16 KB
    __shared__ int hist[256], sc[256], lbase[256], lcur[256], gbase[256];
    int tid = threadIdx.x;
    int e0 = blockIdx.x * CHUNK;
    int total = min(CHUNK, E - e0);
    hist[tid] = 0;
    __syncthreads();
    for (int i = tid; i < total; i += 256)
        atomicAdd(&hist[dst[e0 + i] >> BSHIFT], 1);
    __syncthreads();
    sc[tid] = hist[tid];
    __syncthreads();
    for (int off = 1; off < 256; off <<= 1) {
        int v = (tid >= off) ? sc[tid - off] : 0;
        __syncthreads();
        sc[tid] += v;
        __syncthreads();
    }
    lbase[tid] = sc[tid] - hist[tid];
    lcur[tid]  = sc[tid] - hist[tid];
    if (tid < NBUCK) gbase[tid] = chunk_base[blockIdx.x * NBUCK + tid];
    __syncthreads();
    for (int i = tid; i < total; i += 256) {
        unsigned int s = (unsigned int)src[e0 + i];
        unsigned int d = (unsigned int)dst[e0 + i];
        int pos = atomicAdd(&lcur[d >> BSHIFT], 1);
        stage[pos] = (d << 16) | s;
    }
    __syncthreads();
    for (int i = tid; i < total; i += 256) {
        unsigned int p = stage[i];
        int b = (int)(p >> 24);                          // dst >> 8
        pairs[gbase[b] + (i - lbase[b])] = p;            // coalesced per segment
    }
}

// ---------- pass 4: per-bucket counting sort -> csr(ushort), rowptr, dinv ----------
__global__ __launch_bounds__(256) void bucket_sort_kernel(
        const unsigned int* __restrict__ pairs, const int* __restrict__ base,
        unsigned short* __restrict__ csr, int* __restrict__ rowptr,
        float* __restrict__ dinv, int N) {
    __shared__ int cntl[256], sc[256], cur[256];
    int tid = threadIdx.x;
    int b = blockIdx.x;
    int pbase = base[b], pend = base[b + 1];
    int cnt = pend - pbase;
    cntl[tid] = 0;
    __syncthreads();
    for (int i = tid; i < cnt; i += 256)
        atomicAdd(&cntl[(pairs[pbase + i] >> 16) & 255u], 1);
    __syncthreads();
    sc[tid] = cntl[tid];
    __syncthreads();
    for (int off = 1; off < 256; off <<= 1) {
        int v = (tid >= off) ? sc[tid - off] : 0;
        __syncthreads();
        sc[tid] += v;
        __syncthreads();
    }
    int excl = sc[tid] - cntl[tid];
    cur[tid] = excl;
    int v = (b << BSHIFT) + tid;
    if (v < N) {
        rowptr[v] = pbase + excl;
        dinv[v] = rsqrtf((float)(cntl[tid] + 1));  // deg = indeg + 1 (self loop)
    }
    __syncthreads();
    for (int i = tid; i < cnt; i += 256) {
        unsigned int p = pairs[pbase + i];
        int pos = atomicAdd(&cur[(p >> 16) & 255u], 1);
        csr[pbase + pos] = (unsigned short)(p & 0xffffu);
    }
}

// ---------- layer 1 GEMM (f32 input) + dinv prescale -> bf16 messages ----------
template <int K>
__global__ __launch_bounds__(256) void gemm_f32_kernel(
        const float* __restrict__ X, const float* __restrict__ W,
        const float* __restrict__ dinv, unsigned short* __restrict__ G, int N) {
    constexpr int KC  = 64;
    constexpr int XLD = KC + 4;
    __shared__ float Xs[64 * XLD];        // 17408 B
    __shared__ float Wls[KC * CH];        // 16384 B
    int tid = threadIdx.x;
    int tx  = tid & 15;
    int ty  = tid >> 4;
    int row_tile = blockIdx.x * 64;
    int r0 = ty * 4;
    float acc[4][4] = {{0.f}};

    for (int kc = 0; kc < K; kc += KC) {
        __syncthreads();
#pragma unroll
        for (int t = 0; t < 4; ++t) {
            int idx = tid + t * 256;
            int row = idx >> 4;
            int k4  = idx & 15;
            int grow = row_tile + row;
            const float4* xs = (const float4*)(X + (size_t)min(grow, N - 1) * K + kc);
            *(float4*)&Xs[row * XLD + 4 * k4] = xs[k4];
        }
#pragma unroll
        for (int t = 0; t < 4; ++t) {
            int idx = tid + t * 256;
            *(float4*)&Wls[idx * 4] = ((const float4*)(W + (size_t)kc * CH))[idx];
        }
        __syncthreads();
#pragma unroll
        for (int kk = 0; kk < KC; kk += 4) {
            float xr[4][4], wr[4][4];
#pragma unroll
            for (int i = 0; i < 4; ++i) {
                float4 v = *(const float4*)&Xs[(r0 + i) * XLD + kk];
                xr[i][0] = v.x; xr[i][1] = v.y; xr[i][2] = v.z; xr[i][3] = v.w;
            }
#pragma unroll
            for (int j = 0; j < 4; ++j) {
                float4 v = *(const float4*)&Wls[(kk + j) * CH + 4 * tx];
                wr[j][0] = v.x; wr[j][1] = v.y; wr[j][2] = v.z; wr[j][3] = v.w;
            }
#pragma unroll
            for (int i = 0; i < 4; ++i)
#pragma unroll
                for (int j = 0; j < 4; ++j)
#pragma unroll
                    for (int c = 0; c < 4; ++c)
                        acc[i][c] = fmaf(xr[i][j], wr[j][c], acc[i][c]);
        }
    }
#pragma unroll
    for (int i = 0; i < 4; ++i) {
        int r = row_tile + r0 + i;
        if (r < N) {
            float d = dinv[r];
            ushort4 o;
            o.x = f2bf_rne(acc[i][0] * d);
            o.y = f2bf_rne(acc[i][1] * d);
            o.z = f2bf_rne(acc[i][2] * d);
            o.w = f2bf_rne(acc[i][3] * d);
            ((ushort4*)G)[(size_t)r * 16 + tx] = o;
        }
    }
}

// ---------- fused layer: h = relu(dinv ⊙ agg(Gin)) in LDS; Gout = bf16(dinv ⊙ h@W) ----------
// 512 threads = 8 waves. Phase A: 8 nodes/wave, 8 lanes/node (uint4 = 8 bf16 ch).
// Phase B: 64x64 GEMM from LDS, 2x4 per thread.
__global__ __launch_bounds__(512) void fused_layer_kernel(
        const unsigned short* __restrict__ Gin, const int* __restrict__ rowptr,
        const unsigned short* __restrict__ csr, const float* __restrict__ dinv,
        const float* __restrict__ W, unsigned short* __restrict__ Gout,
        int N, int E) {
    constexpr int XLDU = 36;                 // dwords per LDS row (32 + pad)
    __shared__ unsigned int Xs[64 * XLDU];   // 9216 B (bf16 h tile)
    __shared__ float Wls[64 * CH];           // 16384 B
    int tid = threadIdx.x;
#pragma unroll
    for (int t = 0; t < 2; ++t) {
        int idx = tid + t * 512;             // 0..1023
        *(float4*)&Wls[idx * 4] = ((const float4*)W)[idx];
    }
    // ---- phase A ----
    int lane = tid & 63;
    int grp = lane >> 3, cl = lane & 7;
    int vl = (tid >> 6) * 8 + grp;           // local row 0..63
    int v = blockIdx.x * 64 + vl;
    bool valid = v < N;
    int vc = valid ? v : N - 1;
    int beg = rowptr[vc];
    int cnt = valid ? rowptr[vc + 1] - beg : 0;
    int mx = cnt;
    mx = max(mx, __shfl_xor(mx, 8));
    mx = max(mx, __shfl_xor(mx, 16));
    mx = max(mx, __shfl_xor(mx, 32));
    const uint4* __restrict__ G4 = (const uint4*)Gin;
    float a0 = 0.f, a1 = 0.f, a2 = 0.f, a3 = 0.f;
    float a4 = 0.f, a5 = 0.f, a6 = 0.f, a7 = 0.f;
#pragma unroll 2
    for (int it = 0; it < mx; ++it) {
        int eg = min(beg + it, E - 1);
        bool ok = it < cnt;
        int u = ok ? (int)csr[eg] : 0;
        float s = ok ? 1.f : 0.f;
        uint4 q = G4[(size_t)u * 8 + cl];
        a0 = fmaf(bf_lo(q.x), s, a0); a1 = fmaf(bf_hi(q.x), s, a1);
        a2 = fmaf(bf_lo(q.y), s, a2); a3 = fmaf(bf_hi(q.y), s, a3);
        a4 = fmaf(bf_lo(q.z), s, a4); a5 = fmaf(bf_hi(q.z), s, a5);
        a6 = fmaf(bf_lo(q.w), s, a6); a7 = fmaf(bf_hi(q.w), s, a7);
    }
    {
        uint4 q = G4[(size_t)vc * 8 + cl];   // self loop
        float d = dinv[vc];
        float o0 = fmaxf((a0 + bf_lo(q.x)) * d, 0.f);
        float o1 = fmaxf((a1 + bf_hi(q.x)) * d, 0.f);
        float o2 = fmaxf((a2 + bf_lo(q.y)) * d, 0.f);
        float o3 = fmaxf((a3 + bf_hi(q.y)) * d, 0.f);
        float o4 = fmaxf((a4 + bf_lo(q.z)) * d, 0.f);
        float o5 = fmaxf((a5 + bf_hi(q.z)) * d, 0.f);
        float o6 = fmaxf((a6 + bf_lo(q.w)) * d, 0.f);
        float o7 = fmaxf((a7 + bf_hi(q.w)) * d, 0.f);
        uint4 p;
        p.x = pack2bf(o0, o1); p.y = pack2bf(o2, o3);
        p.z = pack2bf(o4, o5); p.w = pack2bf(o6, o7);
        *(uint4*)&Xs[vl * XLDU + cl * 4] = p;
    }
    __syncthreads();
    // ---- phase B ----
    int tx = tid & 15, ty = tid >> 4;        // ty 0..31
    int r0 = ty * 2;
    float acc[2][4] = {{0.f}};
#pragma unroll
    for (int kk = 0; kk < 64; kk += 4) {
        float xr[2][4], wr[4][4];
#pragma unroll
        for (int i = 0; i < 2; ++i) {
            uint2 qq = *(const uint2*)&Xs[(r0 + i) * XLDU + (kk >> 1)];
            xr[i][0] = bf_lo(qq.x); xr[i][1] = bf_hi(qq.x);
            xr[i][2] = bf_lo(qq.y); xr[i][3] = bf_hi(qq.y);
        }
#pragma unroll
        for (int j = 0; j < 4; ++j) {
            float4 vv = *(const float4*)&Wls[(kk + j) * CH + 4 * tx];
            wr[j][0] = vv.x; wr[j][1] = vv.y; wr[j][2] = vv.z; wr[j][3] = vv.w;
        }
#pragma unroll
        for (int i = 0; i < 2; ++i)
#pragma unroll
            for (int j = 0; j < 4; ++j)
#pragma unroll
                for (int c = 0; c < 4; ++c)
                    acc[i][c] = fmaf(xr[i][j], wr[j][c], acc[i][c]);
    }
#pragma unroll
    for (int i = 0; i < 2; ++i) {
        int r = blockIdx.x * 64 + r0 + i;
        if (r < N) {
            float d = dinv[r];
            ushort4 o;
            o.x = f2bf_rne(acc[i][0] * d);
            o.y = f2bf_rne(acc[i][1] * d);
            o.z = f2bf_rne(acc[i][2] * d);
            o.w = f2bf_rne(acc[i][3] * d);
            ((ushort4*)Gout)[(size_t)r * 16 + tx] = o;
        }
    }
}

// ---------- final aggregation (layer 3, f32 out, no relu) ----------
__global__ __launch_bounds__(256) void aggregate_f32_kernel(
        const unsigned short* __restrict__ G, const int* __restrict__ rowptr,
        const unsigned short* __restrict__ csr, const float* __restrict__ dinv,
        float* __restrict__ Out, int N, int E) {
    int lane = threadIdx.x & 63;
    int w = (blockIdx.x * 256 + threadIdx.x) >> 6;
    int grp = lane >> 3, cl = lane & 7;
    int v = w * 8 + grp;
    bool valid = v < N;
    int vc = valid ? v : N - 1;
    int beg = rowptr[vc];
    int cnt = valid ? rowptr[vc + 1] - beg : 0;
    int mx = cnt;
    mx = max(mx, __shfl_xor(mx, 8));
    mx = max(mx, __shfl_xor(mx, 16));
    mx = max(mx, __shfl_xor(mx, 32));
    const uint4* __restrict__ G4 = (const uint4*)G;
    float a0 = 0.f, a1 = 0.f, a2 = 0.f, a3 = 0.f;
    float a4 = 0.f, a5 = 0.f, a6 = 0.f, a7 = 0.f;
#pragma unroll 2
    for (int it = 0; it < mx; ++it) {
        int eg = min(beg + it, E - 1);
        bool ok = it < cnt;
        int u = ok ? (int)csr[eg] : 0;
        float s = ok ? 1.f : 0.f;
        uint4 q = G4[(size_t)u * 8 + cl];
        a0 = fmaf(bf_lo(q.x), s, a0); a1 = fmaf(bf_hi(q.x), s, a1);
        a2 = fmaf(bf_lo(q.y), s, a2); a3 = fmaf(bf_hi(q.y), s, a3);
        a4 = fmaf(bf_lo(q.z), s, a4); a5 = fmaf(bf_hi(q.z), s, a5);
        a6 = fmaf(bf_lo(q.w), s, a6); a7 = fmaf(bf_hi(q.w), s, a7);
    }
    if (valid) {
        uint4 q = G4[(size_t)v * 8 + cl];
        float d = dinv[v];
        float4 w0, w1;
        w0.x = (a0 + bf_lo(q.x)) * d; w0.y = (a1 + bf_hi(q.x)) * d;
        w0.z = (a2 + bf_lo(q.y)) * d; w0.w = (a3 + bf_hi(q.y)) * d;
        w1.x = (a4 + bf_lo(q.z)) * d; w1.y = (a5 + bf_hi(q.z)) * d;
        w1.z = (a6 + bf_lo(q.w)) * d; w1.w = (a7 + bf_hi(q.w)) * d;
        ((float4*)Out)[(size_t)v * 16 + cl * 2]     = w0;
        ((float4*)Out)[(size_t)v * 16 + cl * 2 + 1] = w1;
    }
}

// ---------- fused mean-pool + linear head ----------
__global__ __launch_bounds__(64) void pool_head_kernel(
        const float* __restrict__ H, const int* __restrict__ gptr,
        const float* __restrict__ Wl, const float* __restrict__ bl,
        float* __restrict__ out, int NG) {
    int g = blockIdx.x;
    int lane = threadIdx.x;  // 64 = CH
    int s = gptr[g], e = gptr[g + 1];
    float acc = 0.f;
    for (int v = s; v < e; ++v) acc += H[(size_t)v * CH + lane];
    float c = (float)(e - s);
    float mean = (c > 0.f) ? acc / c : 0.f;
    for (int o = 0; o < 10; ++o) {
        float t = mean * Wl[lane * 10 + o];
        for (int off = 32; off > 0; off >>= 1) t += __shfl_down(t, off);
        if (lane == 0) out[g * 10 + o] = t + bl[o];
    }
}

extern "C" void kernel_launch(void* const* d_in, const int* in_sizes, int n_in,
                              void* d_out, int out_size, void* d_ws, size_t ws_size,
                              hipStream_t stream) {
    const float* x     = (const float*)d_in[0];
    const int*   ei    = (const int*)d_in[1];
    const int*   batch = (const int*)d_in[2];
    const float* W1    = (const float*)d_in[3];
    const float* W2    = (const float*)d_in[4];
    const float* W3    = (const float*)d_in[5];
    const float* Wl    = (const float*)d_in[6];
    const float* bl    = (const float*)d_in[7];
    float* out = (float*)d_out;

    const int N  = in_sizes[0] / 128;  // 50000 (< 65536)
    const int E  = in_sizes[1] / 2;    // 1250000
    const int NG = out_size / 10;      // 500

    const int* src = ei;
    const int* dst = ei + E;

    const int cb = (E + CHUNK - 1) / CHUNK;  // 306

    // workspace carve-out (256B aligned)
    char* ws = (char*)d_ws;
    size_t off = 0;
    auto alloc = [&](size_t bytes) -> void* {
        void* p = ws + off;
        off += bytes;
        off = (off + 255) & ~(size_t)255;
        return p;
    };
    int*   chunk_hist  = (int*)alloc((size_t)cb * NBUCK * 4);   // 240KB
    int*   chunk_base  = (int*)alloc((size_t)cb * NBUCK * 4);   // 240KB
    int*   bucket_base = (int*)alloc((size_t)(NBUCK + 1) * 4);
    unsigned short* csr = (unsigned short*)alloc((size_t)(E + 64) * 2);  // 2.5MB
    int*   rowptr = (int*)alloc((size_t)(N + 1) * 4);
    float* dinv   = (float*)alloc((size_t)N * 4);
    int*   gptrb  = (int*)alloc((size_t)(NG + 1) * 4);
    unsigned short* GA = (unsigned short*)alloc((size_t)N * CH * 2);  // 6.4MB
    unsigned short* GB = (unsigned short*)alloc((size_t)N * CH * 2);  // 6.4MB
    float* hbuf   = (float*)alloc((size_t)N * CH * 4);   // 12.8MB; aliases pairs (5MB)
    unsigned int* pairs = (unsigned int*)hbuf;  // consumed by sort before agg3 writes hbuf

    int gb = (N + 63) / 64;            // 782: gemm1 / fused tiles
    int ab = ((N + 7) / 8 + 3) / 4;    // agg3: 8 nodes/wave, 4 waves/block

    bucket_hist_kernel<<<cb, 256, 0, stream>>>(dst, chunk_hist, E);
    scan_gptr_kernel<<<2, 256, 0, stream>>>(chunk_hist, cb, chunk_base, bucket_base,
                                            rowptr, batch, gptrb, N, E, NG);
    bin_kernel<<<cb, 256, 0, stream>>>(src, dst, chunk_base, pairs, E);
    bucket_sort_kernel<<<NBUCK, 256, 0, stream>>>(pairs, bucket_base, csr, rowptr, dinv, N);

    // layer 1: 128 -> 64 (messages G1 = bf16(dinv ⊙ xW1))
    gemm_f32_kernel<128><<<gb, 256, 0, stream>>>(x, W1, dinv, GA, N);
    // layer 2 fused: h1 = relu(dinv⊙agg(G1)); G2 = bf16(dinv ⊙ h1 W2)
    fused_layer_kernel<<<gb, 512, 0, stream>>>(GA, rowptr, csr, dinv, W2, GB, N, E);
    // layer 3 fused: h2 = relu(dinv⊙agg(G2)); G3 = bf16(dinv ⊙ h2 W3)
    fused_layer_kernel<<<gb, 512, 0, stream>>>(GB, rowptr, csr, dinv, W3, GA, N, E);
    // final aggregation (no relu) -> f32 h3
    aggregate_f32_kernel<<<ab, 256, 0, stream>>>(GA, rowptr, csr, dinv, hbuf, N, E);

    // mean pool + linear head
    pool_head_kernel<<<NG, 64, 0, stream>>>(hbuf, gptrb, Wl, bl, out, NG);
}

// Round 9
// 297.822 us; speedup vs baseline: 2.1159x; 2.1159x over previous
//
#include <hip/hip_runtime.h>

#define CH 64
#define CHUNK 4096
#define BSHIFT 8          // 256 nodes per bucket
#define NBUCK 196         // ceil(50000 / 256); requires N < 65536 (16-bit packing)

__device__ __forceinline__ unsigned short f2bf_rne(float f) {
    unsigned int u = __float_as_uint(f);
    u += 0x7fffu + ((u >> 16) & 1u);   // round to nearest even
    return (unsigned short)(u >> 16);
}
__device__ __forceinline__ float bf_lo(unsigned int q) {
    return __uint_as_float(q << 16);
}
__device__ __forceinline__ float bf_hi(unsigned int q) {
    return __uint_as_float(q & 0xffff0000u);
}
__device__ __forceinline__ unsigned int pack2bf(float lo, float hi) {
    return (unsigned int)f2bf_rne(lo) | ((unsigned int)f2bf_rne(hi) << 16);
}

// ---------- K0: layer-1 GEMM (no dinv, raw messages) + per-chunk histogram ----------
// Blocks [0, gemm_blocks): 64x64 GEMM tile. Blocks [gemm_blocks, +cb): histogram.
// All blocks 256 threads; LDS = 17408+16384+1024 = 34816 B -> 4 blocks/CU.
template <int K>
__global__ __launch_bounds__(256) void gemm1_hist_kernel(
        const float* __restrict__ X, const float* __restrict__ W,
        unsigned short* __restrict__ G, int N,
        const int* __restrict__ dst, int* __restrict__ chunk_hist, int E,
        int gemm_blocks) {
    constexpr int KC  = 64;
    constexpr int XLD = KC + 4;
    __shared__ float Xs[64 * XLD];        // 17408 B
    __shared__ float Wls[KC * CH];        // 16384 B
    __shared__ int hist[256];             // 1024 B
    int tid = threadIdx.x;

    if (blockIdx.x >= gemm_blocks) {
        // ---- histogram part ----
        int cid = blockIdx.x - gemm_blocks;
        int e0 = cid * CHUNK;
        int total = min(CHUNK, E - e0);
        hist[tid] = 0;
        __syncthreads();
        for (int i = tid; i < total; i += 256)
            atomicAdd(&hist[dst[e0 + i] >> BSHIFT], 1);
        __syncthreads();
        if (tid < NBUCK) chunk_hist[cid * NBUCK + tid] = hist[tid];
        return;
    }

    // ---- gemm part: G = bf16(X @ W) ----
    int tx  = tid & 15;
    int ty  = tid >> 4;
    int row_tile = blockIdx.x * 64;
    int r0 = ty * 4;
    float acc[4][4] = {{0.f}};

    for (int kc = 0; kc < K; kc += KC) {
        __syncthreads();
#pragma unroll
        for (int t = 0; t < 4; ++t) {
            int idx = tid + t * 256;
            int row = idx >> 4;
            int k4  = idx & 15;
            int grow = row_tile + row;
            const float4* xs = (const float4*)(X + (size_t)min(grow, N - 1) * K + kc);
            *(float4*)&Xs[row * XLD + 4 * k4] = xs[k4];
        }
#pragma unroll
        for (int t = 0; t < 4; ++t) {
            int idx = tid + t * 256;
            *(float4*)&Wls[idx * 4] = ((const float4*)(W + (size_t)kc * CH))[idx];
        }
        __syncthreads();
#pragma unroll
        for (int kk = 0; kk < KC; kk += 4) {
            float xr[4][4], wr[4][4];
#pragma unroll
            for (int i = 0; i < 4; ++i) {
                float4 v = *(const float4*)&Xs[(r0 + i) * XLD + kk];
                xr[i][0] = v.x; xr[i][1] = v.y; xr[i][2] = v.z; xr[i][3] = v.w;
            }
#pragma unroll
            for (int j = 0; j < 4; ++j) {
                float4 v = *(const float4*)&Wls[(kk + j) * CH + 4 * tx];
                wr[j][0] = v.x; wr[j][1] = v.y; wr[j][2] = v.z; wr[j][3] = v.w;
            }
#pragma unroll
            for (int i = 0; i < 4; ++i)
#pragma unroll
                for (int j = 0; j < 4; ++j)
#pragma unroll
                    for (int c = 0; c < 4; ++c)
                        acc[i][c] = fmaf(xr[i][j], wr[j][c], acc[i][c]);
        }
    }
#pragma unroll
    for (int i = 0; i < 4; ++i) {
        int r = row_tile + r0 + i;
        if (r < N) {
            ushort4 o;
            o.x = f2bf_rne(acc[i][0]);
            o.y = f2bf_rne(acc[i][1]);
            o.z = f2bf_rne(acc[i][2]);
            o.w = f2bf_rne(acc[i][3]);
            ((ushort4*)G)[(size_t)r * 16 + tx] = o;
        }
    }
}

// ---------- pass 2: column-scan chunk hists -> per-chunk bases; block 1: gptr ----------
__global__ __launch_bounds__(256) void scan_gptr_kernel(
        const int* __restrict__ chunk_hist, int cb,
        int* __restrict__ chunk_base, int* __restrict__ bucket_base,
        int* __restrict__ rowptr,
        const int* __restrict__ batch, int* __restrict__ gptr,
        int N, int E, int NG) {
    if (blockIdx.x == 0) {
        __shared__ int sc[256];
        int t = threadIdx.x;
        int total = 0;
        if (t < NBUCK)
            for (int c = 0; c < cb; ++c) total += chunk_hist[c * NBUCK + t];
        sc[t] = total;
        __syncthreads();
        for (int off = 1; off < 256; off <<= 1) {
            int v = (t >= off) ? sc[t - off] : 0;
            __syncthreads();
            sc[t] += v;
            __syncthreads();
        }
        int base = sc[t] - total;   // exclusive prefix over buckets
        if (t < NBUCK) {
            bucket_base[t] = base;
            int run = base;
            for (int c = 0; c < cb; ++c) {
                chunk_base[c * NBUCK + t] = run;
                run += chunk_hist[c * NBUCK + t];
            }
        }
        if (t == NBUCK - 1) bucket_base[NBUCK] = sc[t];
        if (t == 0) rowptr[N] = E;
    } else {
        for (int g = threadIdx.x; g <= NG; g += 256) {
            if (g == NG) { gptr[NG] = N; continue; }
            int lo = 0, hi = N;
            while (lo < hi) {
                int mid = (lo + hi) >> 1;
                if (batch[mid] < g) lo = mid + 1; else hi = mid;
            }
            gptr[g] = lo;
        }
    }
}

// ---------- pass 3: bin edges into bucket regions (no global atomics) ----------
__global__ __launch_bounds__(256) void bin_kernel(
        const int* __restrict__ src, const int* __restrict__ dst,
        const int* __restrict__ chunk_base, unsigned int* __restrict__ pairs, int E) {
    __shared__ unsigned int stage[CHUNK];                 // 16 KB
    __shared__ int hist[256], sc[256], lbase[256], lcur[256], gbase[256];
    int tid = threadIdx.x;
    int e0 = blockIdx.x * CHUNK;
    int total = min(CHUNK, E - e0);
    hist[tid] = 0;
    __syncthreads();
    for (int i = tid; i < total; i += 256)
        atomicAdd(&hist[dst[e0 + i] >> BSHIFT], 1);
    __syncthreads();
    sc[tid] = hist[tid];
    __syncthreads();
    for (int off = 1; off < 256; off <<= 1) {
        int v = (tid >= off) ? sc[tid - off] : 0;
        __syncthreads();
        sc[tid] += v;
        __syncthreads();
    }
    lbase[tid] = sc[tid] - hist[tid];
    lcur[tid]  = sc[tid] - hist[tid];
    if (tid < NBUCK) gbase[tid] = chunk_base[blockIdx.x * NBUCK + tid];
    __syncthreads();
    for (int i = tid; i < total; i += 256) {
        unsigned int s = (unsigned int)src[e0 + i];
        unsigned int d = (unsigned int)dst[e0 + i];
        int pos = atomicAdd(&lcur[d >> BSHIFT], 1);
        stage[pos] = (d << 16) | s;
    }
    __syncthreads();
    for (int i = tid; i < total; i += 256) {
        unsigned int p = stage[i];
        int b = (int)(p >> 24);
        pairs[gbase[b] + (i - lbase[b])] = p;
    }
}

// ---------- pass 4: per-bucket counting sort -> csr(ushort), rowptr, dinv ----------
__global__ __launch_bounds__(256) void bucket_sort_kernel(
        const unsigned int* __restrict__ pairs, const int* __restrict__ base,
        unsigned short* __restrict__ csr, int* __restrict__ rowptr,
        float* __restrict__ dinv, int N) {
    __shared__ int cntl[256], sc[256], cur[256];
    int tid = threadIdx.x;
    int b = blockIdx.x;
    int pbase = base[b], pend = base[b + 1];
    int cnt = pend - pbase;
    cntl[tid] = 0;
    __syncthreads();
    for (int i = tid; i < cnt; i += 256)
        atomicAdd(&cntl[(pairs[pbase + i] >> 16) & 255u], 1);
    __syncthreads();
    sc[tid] = cntl[tid];
    __syncthreads();
    for (int off = 1; off < 256; off <<= 1) {
        int v = (tid >= off) ? sc[tid - off] : 0;
        __syncthreads();
        sc[tid] += v;
        __syncthreads();
    }
    int excl = sc[tid] - cntl[tid];
    cur[tid] = excl;
    int v = (b << BSHIFT) + tid;
    if (v < N) {
        rowptr[v] = pbase + excl;
        dinv[v] = rsqrtf((float)(cntl[tid] + 1));  // deg = indeg + 1 (self loop)
    }
    __syncthreads();
    for (int i = tid; i < cnt; i += 256) {
        unsigned int p = pairs[pbase + i];
        int pos = atomicAdd(&cur[(p >> 16) & 255u], 1);
        csr[pbase + pos] = (unsigned short)(p & 0xffffu);
    }
}

// ---------- gather aggregation ----------
// 8 nodes/wave, 8 lanes/node (uint4 = 8 bf16 channels). PRESCALED: messages
// already carry dinv[u]; else multiply each gathered row by dinv[u].
template <bool PRESCALED, bool F32OUT>
__global__ __launch_bounds__(256) void aggregate_kernel(
        const unsigned short* __restrict__ G, const int* __restrict__ rowptr,
        const unsigned short* __restrict__ csr, const float* __restrict__ dinv,
        void* __restrict__ Out, int N, int E, int relu) {
    int lane = threadIdx.x & 63;
    int w = (blockIdx.x * 256 + threadIdx.x) >> 6;
    int grp = lane >> 3, cl = lane & 7;
    int v = w * 8 + grp;
    bool valid = v < N;
    int vc = valid ? v : N - 1;
    int beg = rowptr[vc];
    int cnt = valid ? rowptr[vc + 1] - beg : 0;
    int mx = cnt;
    mx = max(mx, __shfl_xor(mx, 8));
    mx = max(mx, __shfl_xor(mx, 16));
    mx = max(mx, __shfl_xor(mx, 32));

    const uint4* __restrict__ G4 = (const uint4*)G;
    float a0 = 0.f, a1 = 0.f, a2 = 0.f, a3 = 0.f;
    float a4 = 0.f, a5 = 0.f, a6 = 0.f, a7 = 0.f;
#pragma unroll 2
    for (int it = 0; it < mx; ++it) {
        int eg = min(beg + it, E - 1);
        bool ok = it < cnt;
        int u = ok ? (int)csr[eg] : 0;
        float s;
        if (PRESCALED) s = ok ? 1.f : 0.f;
        else           s = ok ? dinv[u] : 0.f;
        uint4 q = G4[(size_t)u * 8 + cl];
        a0 = fmaf(bf_lo(q.x), s, a0); a1 = fmaf(bf_hi(q.x), s, a1);
        a2 = fmaf(bf_lo(q.y), s, a2); a3 = fmaf(bf_hi(q.y), s, a3);
        a4 = fmaf(bf_lo(q.z), s, a4); a5 = fmaf(bf_hi(q.z), s, a5);
        a6 = fmaf(bf_lo(q.w), s, a6); a7 = fmaf(bf_hi(q.w), s, a7);
    }
    if (valid) {
        uint4 q = G4[(size_t)v * 8 + cl];   // self-loop term
        float d = dinv[v];
        float sv = PRESCALED ? 1.f : d;     // self message also carries dinv[v]
        float o0 = (a0 + bf_lo(q.x) * sv) * d, o1 = (a1 + bf_hi(q.x) * sv) * d;
        float o2 = (a2 + bf_lo(q.y) * sv) * d, o3 = (a3 + bf_hi(q.y) * sv) * d;
        float o4 = (a4 + bf_lo(q.z) * sv) * d, o5 = (a5 + bf_hi(q.z) * sv) * d;
        float o6 = (a6 + bf_lo(q.w) * sv) * d, o7 = (a7 + bf_hi(q.w) * sv) * d;
        if (relu) {
            o0 = fmaxf(o0, 0.f); o1 = fmaxf(o1, 0.f); o2 = fmaxf(o2, 0.f);
            o3 = fmaxf(o3, 0.f); o4 = fmaxf(o4, 0.f); o5 = fmaxf(o5, 0.f);
            o6 = fmaxf(o6, 0.f); o7 = fmaxf(o7, 0.f);
        }
        if (F32OUT) {
            float4 w0 = {o0, o1, o2, o3}, w1 = {o4, o5, o6, o7};
            ((float4*)Out)[(size_t)v * 16 + cl * 2]     = w0;
            ((float4*)Out)[(size_t)v * 16 + cl * 2 + 1] = w1;
        } else {
            uint4 p;
            p.x = pack2bf(o0, o1); p.y = pack2bf(o2, o3);
            p.z = pack2bf(o4, o5); p.w = pack2bf(o6, o7);
            ((uint4*)Out)[(size_t)v * 8 + cl] = p;
        }
    }
}

// ---------- GEMM (bf16 input, K=64) + dinv prescale -> bf16 ----------
__global__ __launch_bounds__(256) void gemm_bf16_kernel(
        const unsigned short* __restrict__ Xbf, const float* __restrict__ W,
        const float* __restrict__ dinv, unsigned short* __restrict__ G, int N) {
    constexpr int XLDU = 36;
    __shared__ unsigned int Xs[64 * XLDU];  // 9216 B
    __shared__ float Wls[64 * CH];          // 16384 B
    int tid = threadIdx.x;
    int tx  = tid & 15;
    int ty  = tid >> 4;
    int row_tile = blockIdx.x * 64;
    int r0 = ty * 4;
    float acc[4][4] = {{0.f}};

#pragma unroll
    for (int t = 0; t < 2; ++t) {
        int idx = tid + t * 256;
        int row = idx >> 3;
        int k4  = idx & 7;
        int grow = row_tile + row;
        uint4 v = ((const uint4*)Xbf)[(size_t)min(grow, N - 1) * 8 + k4];
        *(uint4*)&Xs[row * XLDU + 4 * k4] = v;
    }
#pragma unroll
    for (int t = 0; t < 4; ++t) {
        int idx = tid + t * 256;
        *(float4*)&Wls[idx * 4] = ((const float4*)W)[idx];
    }
    __syncthreads();
#pragma unroll
    for (int kk = 0; kk < 64; kk += 4) {
        float xr[4][4], wr[4][4];
#pragma unroll
        for (int i = 0; i < 4; ++i) {
            uint2 q = *(const uint2*)&Xs[(r0 + i) * XLDU + (kk >> 1)];
            xr[i][0] = bf_lo(q.x); xr[i][1] = bf_hi(q.x);
            xr[i][2] = bf_lo(q.y); xr[i][3] = bf_hi(q.y);
        }
#pragma unroll
        for (int j = 0; j < 4; ++j) {
            float4 v = *(const float4*)&Wls[(kk + j) * CH + 4 * tx];
            wr[j][0] = v.x; wr[j][1] = v.y; wr[j][2] = v.z; wr[j][3] = v.w;
        }
#pragma unroll
        for (int i = 0; i < 4; ++i)
#pragma unroll
            for (int j = 0; j < 4; ++j)
#pragma unroll
                for (int c = 0; c < 4; ++c)
                    acc[i][c] = fmaf(xr[i][j], wr[j][c], acc[i][c]);
    }
#pragma unroll
    for (int i = 0; i < 4; ++i) {
        int r = row_tile + r0 + i;
        if (r < N) {
            float d = dinv[r];
            ushort4 o;
            o.x = f2bf_rne(acc[i][0] * d);
            o.y = f2bf_rne(acc[i][1] * d);
            o.z = f2bf_rne(acc[i][2] * d);
            o.w = f2bf_rne(acc[i][3] * d);
            ((ushort4*)G)[(size_t)r * 16 + tx] = o;
        }
    }
}

// ---------- fused mean-pool + linear head ----------
__global__ __launch_bounds__(64) void pool_head_kernel(
        const float* __restrict__ H, const int* __restrict__ gptr,
        const float* __restrict__ Wl, const float* __restrict__ bl,
        float* __restrict__ out, int NG) {
    int g = blockIdx.x;
    int lane = threadIdx.x;  // 64 = CH
    int s = gptr[g], e = gptr[g + 1];
    float acc = 0.f;
    for (int v = s; v < e; ++v) acc += H[(size_t)v * CH + lane];
    float c = (float)(e - s);
    float mean = (c > 0.f) ? acc / c : 0.f;
    for (int o = 0; o < 10; ++o) {
        float t = mean * Wl[lane * 10 + o];
        for (int off = 32; off > 0; off >>= 1) t += __shfl_down(t, off);
        if (lane == 0) out[g * 10 + o] = t + bl[o];
    }
}

extern "C" void kernel_launch(void* const* d_in, const int* in_sizes, int n_in,
                              void* d_out, int out_size, void* d_ws, size_t ws_size,
                              hipStream_t stream) {
    const float* x     = (const float*)d_in[0];
    const int*   ei    = (const int*)d_in[1];
    const int*   batch = (const int*)d_in[2];
    const float* W1    = (const float*)d_in[3];
    const float* W2    = (const float*)d_in[4];
    const float* W3    = (const float*)d_in[5];
    const float* Wl    = (const float*)d_in[6];
    const float* bl    = (const float*)d_in[7];
    float* out = (float*)d_out;

    const int N  = in_sizes[0] / 128;  // 50000 (< 65536)
    const int E  = in_sizes[1] / 2;    // 1250000
    const int NG = out_size / 10;      // 500

    const int* src = ei;
    const int* dst = ei + E;

    const int cb = (E + CHUNK - 1) / CHUNK;  // 306

    // workspace carve-out (256B aligned)
    char* ws = (char*)d_ws;
    size_t off = 0;
    auto alloc = [&](size_t bytes) -> void* {
        void* p = ws + off;
        off += bytes;
        off = (off + 255) & ~(size_t)255;
        return p;
    };
    int*   chunk_hist  = (int*)alloc((size_t)cb * NBUCK * 4);
    int*   chunk_base  = (int*)alloc((size_t)cb * NBUCK * 4);
    int*   bucket_base = (int*)alloc((size_t)(NBUCK + 1) * 4);
    unsigned short* csr = (unsigned short*)alloc((size_t)(E + 64) * 2);
    int*   rowptr = (int*)alloc((size_t)(N + 1) * 4);
    float* dinv   = (float*)alloc((size_t)N * 4);
    int*   gptrb  = (int*)alloc((size_t)(NG + 1) * 4);
    unsigned short* GA = (unsigned short*)alloc((size_t)N * CH * 2);  // 6.4MB
    unsigned short* GB = (unsigned short*)alloc((size_t)N * CH * 2);  // 6.4MB
    float* hbuf   = (float*)alloc((size_t)N * CH * 4);   // 12.8MB; aliases pairs (5MB)
    unsigned int* pairs = (unsigned int*)hbuf;  // sort consumes before agg3 writes hbuf

    int gb = (N + 63) / 64;            // 782 gemm tiles
    int ab = ((N + 7) / 8 + 3) / 4;    // agg: 8 nodes/wave, 4 waves/block

    // K0: gemm1 (raw messages, no dinv) + per-chunk histogram in one launch
    gemm1_hist_kernel<128><<<gb + cb, 256, 0, stream>>>(x, W1, GA, N,
                                                        dst, chunk_hist, E, gb);
    scan_gptr_kernel<<<2, 256, 0, stream>>>(chunk_hist, cb, chunk_base, bucket_base,
                                            rowptr, batch, gptrb, N, E, NG);
    bin_kernel<<<cb, 256, 0, stream>>>(src, dst, chunk_base, pairs, E);
    bucket_sort_kernel<<<NBUCK, 256, 0, stream>>>(pairs, bucket_base, csr, rowptr, dinv, N);

    // layer 1 aggregate (messages NOT prescaled -> multiply dinv[u] per edge)
    aggregate_kernel<false, false><<<ab, 256, 0, stream>>>(GA, rowptr, csr, dinv,
                                                           GB, N, E, 1);
    // layer 2
    gemm_bf16_kernel<<<gb, 256, 0, stream>>>(GB, W2, dinv, GA, N);
    aggregate_kernel<true, false><<<ab, 256, 0, stream>>>(GA, rowptr, csr, dinv,
                                                          GB, N, E, 1);
    // layer 3
    gemm_bf16_kernel<<<gb, 256, 0, stream>>>(GB, W3, dinv, GA, N);
    aggregate_kernel<true, true><<<ab, 256, 0, stream>>>(GA, rowptr, csr, dinv,
                                                         hbuf, N, E, 0);

    // mean pool + linear head
    pool_head_kernel<<<NG, 64, 0, stream>>>(hbuf, gptrb, Wl, bl, out, NG);
}

// Round 10
// 247.466 us; speedup vs baseline: 2.5464x; 1.2035x over previous
//
#include <hip/hip_runtime.h>

#define CH 64
#define CHUNK 4096
#define BSHIFT 8          // 256 nodes per bucket
#define NBUCK 196         // ceil(50000 / 256); requires N < 65536 (16-bit packing)

__device__ __forceinline__ unsigned short f2bf_rne(float f) {
    unsigned int u = __float_as_uint(f);
    u += 0x7fffu + ((u >> 16) & 1u);   // round to nearest even
    return (unsigned short)(u >> 16);
}
__device__ __forceinline__ float bf_lo(unsigned int q) {
    return __uint_as_float(q << 16);
}
__device__ __forceinline__ float bf_hi(unsigned int q) {
    return __uint_as_float(q & 0xffff0000u);
}
__device__ __forceinline__ unsigned int pack2bf(float lo, float hi) {
    return (unsigned int)f2bf_rne(lo) | ((unsigned int)f2bf_rne(hi) << 16);
}

// ---------- K0: layer-1 GEMM (raw messages, no dinv) + global bucket histogram ----------
// Blocks [0, gemm_blocks): 64x64 GEMM tile. Blocks [gemm_blocks, +cb): histogram
// chunks that atomic-add into the global 196-entry bucket_cnt (~60K atomics total).
template <int K>
__global__ __launch_bounds__(256) void gemm1_hist_kernel(
        const float* __restrict__ X, const float* __restrict__ W,
        unsigned short* __restrict__ G, int N,
        const int* __restrict__ dst, int* __restrict__ bucket_cnt, int E,
        int gemm_blocks) {
    constexpr int KC  = 64;
    constexpr int XLD = KC + 4;
    __shared__ float Xs[64 * XLD];        // 17408 B
    __shared__ float Wls[KC * CH];        // 16384 B
    __shared__ int hist[256];             // 1024 B
    int tid = threadIdx.x;

    if (blockIdx.x >= gemm_blocks) {
        int cid = blockIdx.x - gemm_blocks;
        int e0 = cid * CHUNK;
        int total = min(CHUNK, E - e0);
        hist[tid] = 0;
        __syncthreads();
        for (int i = tid; i < total; i += 256)
            atomicAdd(&hist[dst[e0 + i] >> BSHIFT], 1);
        __syncthreads();
        if (tid < NBUCK && hist[tid]) atomicAdd(&bucket_cnt[tid], hist[tid]);
        return;
    }

    // ---- gemm part: G = bf16(X @ W) ----
    int tx  = tid & 15;
    int ty  = tid >> 4;
    int row_tile = blockIdx.x * 64;
    int r0 = ty * 4;
    float acc[4][4] = {{0.f}};

    for (int kc = 0; kc < K; kc += KC) {
        __syncthreads();
#pragma unroll
        for (int t = 0; t < 4; ++t) {
            int idx = tid + t * 256;
            int row = idx >> 4;
            int k4  = idx & 15;
            int grow = row_tile + row;
            const float4* xs = (const float4*)(X + (size_t)min(grow, N - 1) * K + kc);
            *(float4*)&Xs[row * XLD + 4 * k4] = xs[k4];
        }
#pragma unroll
        for (int t = 0; t < 4; ++t) {
            int idx = tid + t * 256;
            *(float4*)&Wls[idx * 4] = ((const float4*)(W + (size_t)kc * CH))[idx];
        }
        __syncthreads();
#pragma unroll
        for (int kk = 0; kk < KC; kk += 4) {
            float xr[4][4], wr[4][4];
#pragma unroll
            for (int i = 0; i < 4; ++i) {
                float4 v = *(const float4*)&Xs[(r0 + i) * XLD + kk];
                xr[i][0] = v.x; xr[i][1] = v.y; xr[i][2] = v.z; xr[i][3] = v.w;
            }
#pragma unroll
            for (int j = 0; j < 4; ++j) {
                float4 v = *(const float4*)&Wls[(kk + j) * CH + 4 * tx];
                wr[j][0] = v.x; wr[j][1] = v.y; wr[j][2] = v.z; wr[j][3] = v.w;
            }
#pragma unroll
            for (int i = 0; i < 4; ++i)
#pragma unroll
                for (int j = 0; j < 4; ++j)
#pragma unroll
                    for (int c = 0; c < 4; ++c)
                        acc[i][c] = fmaf(xr[i][j], wr[j][c], acc[i][c]);
        }
    }
#pragma unroll
    for (int i = 0; i < 4; ++i) {
        int r = row_tile + r0 + i;
        if (r < N) {
            ushort4 o;
            o.x = f2bf_rne(acc[i][0]);
            o.y = f2bf_rne(acc[i][1]);
            o.z = f2bf_rne(acc[i][2]);
            o.w = f2bf_rne(acc[i][3]);
            ((ushort4*)G)[(size_t)r * 16 + tx] = o;
        }
    }
}

// ---------- pass 2: block 0: 196-entry scan -> base+cursor; block 1: gptr ----------
__global__ __launch_bounds__(256) void scan_gptr_kernel(
        const int* __restrict__ cnt,
        int* __restrict__ bucket_base, int* __restrict__ cursor,
        int* __restrict__ rowptr,
        const int* __restrict__ batch, int* __restrict__ gptr,
        int N, int E, int NG) {
    if (blockIdx.x == 0) {
        __shared__ int sc[256];
        int t = threadIdx.x;
        int c = (t < NBUCK) ? cnt[t] : 0;
        sc[t] = c;
        __syncthreads();
        for (int off = 1; off < 256; off <<= 1) {
            int v = (t >= off) ? sc[t - off] : 0;
            __syncthreads();
            sc[t] += v;
            __syncthreads();
        }
        if (t < NBUCK) { bucket_base[t] = sc[t] - c; cursor[t] = sc[t] - c; }
        if (t == NBUCK - 1) bucket_base[NBUCK] = sc[t];
        if (t == 0) rowptr[N] = E;
    } else {
        for (int g = threadIdx.x; g <= NG; g += 256) {
            if (g == NG) { gptr[NG] = N; continue; }
            int lo = 0, hi = N;
            while (lo < hi) {
                int mid = (lo + hi) >> 1;
                if (batch[mid] < g) lo = mid + 1; else hi = mid;
            }
            gptr[g] = lo;
        }
    }
}

// ---------- pass 3: bin edges into bucket regions (cursor atomics, coalesced flush) ----------
__global__ __launch_bounds__(256) void bin_kernel(
        const int* __restrict__ src, const int* __restrict__ dst,
        int* __restrict__ cursor, unsigned int* __restrict__ pairs, int E) {
    __shared__ unsigned int stage[CHUNK];                 // 16 KB
    __shared__ int hist[256], sc[256], lbase[256], lcur[256], gbase[256];
    int tid = threadIdx.x;
    int e0 = blockIdx.x * CHUNK;
    int total = min(CHUNK, E - e0);
    hist[tid] = 0;
    __syncthreads();
    for (int i = tid; i < total; i += 256)
        atomicAdd(&hist[dst[e0 + i] >> BSHIFT], 1);
    __syncthreads();
    sc[tid] = hist[tid];
    __syncthreads();
    for (int off = 1; off < 256; off <<= 1) {
        int v = (tid >= off) ? sc[tid - off] : 0;
        __syncthreads();
        sc[tid] += v;
        __syncthreads();
    }
    lbase[tid] = sc[tid] - hist[tid];
    lcur[tid]  = sc[tid] - hist[tid];
    if (tid < NBUCK && hist[tid] > 0) gbase[tid] = atomicAdd(&cursor[tid], hist[tid]);
    __syncthreads();
    for (int i = tid; i < total; i += 256) {
        unsigned int s = (unsigned int)src[e0 + i];
        unsigned int d = (unsigned int)dst[e0 + i];
        int pos = atomicAdd(&lcur[d >> BSHIFT], 1);
        stage[pos] = (d << 16) | s;
    }
    __syncthreads();
    for (int i = tid; i < total; i += 256) {
        unsigned int p = stage[i];
        int b = (int)(p >> 24);
        pairs[gbase[b] + (i - lbase[b])] = p;
    }
}

// ---------- pass 4: per-bucket counting sort -> csr(ushort), rowptr, dinv ----------
__global__ __launch_bounds__(256) void bucket_sort_kernel(
        const unsigned int* __restrict__ pairs, const int* __restrict__ base,
        unsigned short* __restrict__ csr, int* __restrict__ rowptr,
        float* __restrict__ dinv, int N) {
    __shared__ int cntl[256], sc[256], cur[256];
    int tid = threadIdx.x;
    int b = blockIdx.x;
    int pbase = base[b], pend = base[b + 1];
    int cnt = pend - pbase;
    cntl[tid] = 0;
    __syncthreads();
    for (int i = tid; i < cnt; i += 256)
        atomicAdd(&cntl[(pairs[pbase + i] >> 16) & 255u], 1);
    __syncthreads();
    sc[tid] = cntl[tid];
    __syncthreads();
    for (int off = 1; off < 256; off <<= 1) {
        int v = (tid >= off) ? sc[tid - off] : 0;
        __syncthreads();
        sc[tid] += v;
        __syncthreads();
    }
    int excl = sc[tid] - cntl[tid];
    cur[tid] = excl;
    int v = (b << BSHIFT) + tid;
    if (v < N) {
        rowptr[v] = pbase + excl;
        dinv[v] = rsqrtf((float)(cntl[tid] + 1));  // deg = indeg + 1 (self loop)
    }
    __syncthreads();
    for (int i = tid; i < cnt; i += 256) {
        unsigned int p = pairs[pbase + i];
        int pos = atomicAdd(&cur[(p >> 16) & 255u], 1);
        csr[pbase + pos] = (unsigned short)(p & 0xffffu);
    }
}

// ---------- gather aggregation ----------
// 8 nodes/wave, 8 lanes/node (uint4 = 8 bf16 channels). PRESCALED: messages
// already carry dinv[u]; else multiply each gathered row by dinv[u].
template <bool PRESCALED, bool F32OUT>
__global__ __launch_bounds__(256) void aggregate_kernel(
        const unsigned short* __restrict__ G, const int* __restrict__ rowptr,
        const unsigned short* __restrict__ csr, const float* __restrict__ dinv,
        void* __restrict__ Out, int N, int E, int relu) {
    int lane = threadIdx.x & 63;
    int w = (blockIdx.x * 256 + threadIdx.x) >> 6;
    int grp = lane >> 3, cl = lane & 7;
    int v = w * 8 + grp;
    bool valid = v < N;
    int vc = valid ? v : N - 1;
    int beg = rowptr[vc];
    int cnt = valid ? rowptr[vc + 1] - beg : 0;
    int mx = cnt;
    mx = max(mx, __shfl_xor(mx, 8));
    mx = max(mx, __shfl_xor(mx, 16));
    mx = max(mx, __shfl_xor(mx, 32));

    const uint4* __restrict__ G4 = (const uint4*)G;
    float a0 = 0.f, a1 = 0.f, a2 = 0.f, a3 = 0.f;
    float a4 = 0.f, a5 = 0.f, a6 = 0.f, a7 = 0.f;
#pragma unroll 2
    for (int it = 0; it < mx; ++it) {
        int eg = min(beg + it, E - 1);
        bool ok = it < cnt;
        int u = ok ? (int)csr[eg] : 0;
        float s;
        if (PRESCALED) s = ok ? 1.f : 0.f;
        else           s = ok ? dinv[u] : 0.f;
        uint4 q = G4[(size_t)u * 8 + cl];
        a0 = fmaf(bf_lo(q.x), s, a0); a1 = fmaf(bf_hi(q.x), s, a1);
        a2 = fmaf(bf_lo(q.y), s, a2); a3 = fmaf(bf_hi(q.y), s, a3);
        a4 = fmaf(bf_lo(q.z), s, a4); a5 = fmaf(bf_hi(q.z), s, a5);
        a6 = fmaf(bf_lo(q.w), s, a6); a7 = fmaf(bf_hi(q.w), s, a7);
    }
    if (valid) {
        uint4 q = G4[(size_t)v * 8 + cl];   // self-loop term
        float d = dinv[v];
        float sv = PRESCALED ? 1.f : d;
        float o0 = (a0 + bf_lo(q.x) * sv) * d, o1 = (a1 + bf_hi(q.x) * sv) * d;
        float o2 = (a2 + bf_lo(q.y) * sv) * d, o3 = (a3 + bf_hi(q.y) * sv) * d;
        float o4 = (a4 + bf_lo(q.z) * sv) * d, o5 = (a5 + bf_hi(q.z) * sv) * d;
        float o6 = (a6 + bf_lo(q.w) * sv) * d, o7 = (a7 + bf_hi(q.w) * sv) * d;
        if (relu) {
            o0 = fmaxf(o0, 0.f); o1 = fmaxf(o1, 0.f); o2 = fmaxf(o2, 0.f);
            o3 = fmaxf(o3, 0.f); o4 = fmaxf(o4, 0.f); o5 = fmaxf(o5, 0.f);
            o6 = fmaxf(o6, 0.f); o7 = fmaxf(o7, 0.f);
        }
        if (F32OUT) {
            float4 w0 = {o0, o1, o2, o3}, w1 = {o4, o5, o6, o7};
            ((float4*)Out)[(size_t)v * 16 + cl * 2]     = w0;
            ((float4*)Out)[(size_t)v * 16 + cl * 2 + 1] = w1;
        } else {
            uint4 p;
            p.x = pack2bf(o0, o1); p.y = pack2bf(o2, o3);
            p.z = pack2bf(o4, o5); p.w = pack2bf(o6, o7);
            ((uint4*)Out)[(size_t)v * 8 + cl] = p;
        }
    }
}

// ---------- GEMM (bf16 input, K=64) + dinv prescale -> bf16 ----------
__global__ __launch_bounds__(256) void gemm_bf16_kernel(
        const unsigned short* __restrict__ Xbf, const float* __restrict__ W,
        const float* __restrict__ dinv, unsigned short* __restrict__ G, int N) {
    constexpr int XLDU = 36;
    __shared__ unsigned int Xs[64 * XLDU];  // 9216 B
    __shared__ float Wls[64 * CH];          // 16384 B
    int tid = threadIdx.x;
    int tx  = tid & 15;
    int ty  = tid >> 4;
    int row_tile = blockIdx.x * 64;
    int r0 = ty * 4;
    float acc[4][4] = {{0.f}};

#pragma unroll
    for (int t = 0; t < 2; ++t) {
        int idx = tid + t * 256;
        int row = idx >> 3;
        int k4  = idx & 7;
        int grow = row_tile + row;
        uint4 v = ((const uint4*)Xbf)[(size_t)min(grow, N - 1) * 8 + k4];
        *(uint4*)&Xs[row * XLDU + 4 * k4] = v;
    }
#pragma unroll
    for (int t = 0; t < 4; ++t) {
        int idx = tid + t * 256;
        *(float4*)&Wls[idx * 4] = ((const float4*)W)[idx];
    }
    __syncthreads();
#pragma unroll
    for (int kk = 0; kk < 64; kk += 4) {
        float xr[4][4], wr[4][4];
#pragma unroll
        for (int i = 0; i < 4; ++i) {
            uint2 q = *(const uint2*)&Xs[(r0 + i) * XLDU + (kk >> 1)];
            xr[i][0] = bf_lo(q.x); xr[i][1] = bf_hi(q.x);
            xr[i][2] = bf_lo(q.y); xr[i][3] = bf_hi(q.y);
        }
#pragma unroll
        for (int j = 0; j < 4; ++j) {
            float4 v = *(const float4*)&Wls[(kk + j) * CH + 4 * tx];
            wr[j][0] = v.x; wr[j][1] = v.y; wr[j][2] = v.z; wr[j][3] = v.w;
        }
#pragma unroll
        for (int i = 0; i < 4; ++i)
#pragma unroll
            for (int j = 0; j < 4; ++j)
#pragma unroll
                for (int c = 0; c < 4; ++c)
                    acc[i][c] = fmaf(xr[i][j], wr[j][c], acc[i][c]);
    }
#pragma unroll
    for (int i = 0; i < 4; ++i) {
        int r = row_tile + r0 + i;
        if (r < N) {
            float d = dinv[r];
            ushort4 o;
            o.x = f2bf_rne(acc[i][0] * d);
            o.y = f2bf_rne(acc[i][1] * d);
            o.z = f2bf_rne(acc[i][2] * d);
            o.w = f2bf_rne(acc[i][3] * d);
            ((ushort4*)G)[(size_t)r * 16 + tx] = o;
        }
    }
}

// ---------- fused mean-pool + linear head ----------
__global__ __launch_bounds__(64) void pool_head_kernel(
        const float* __restrict__ H, const int* __restrict__ gptr,
        const float* __restrict__ Wl, const float* __restrict__ bl,
        float* __restrict__ out, int NG) {
    int g = blockIdx.x;
    int lane = threadIdx.x;  // 64 = CH
    int s = gptr[g], e = gptr[g + 1];
    float acc = 0.f;
    for (int v = s; v < e; ++v) acc += H[(size_t)v * CH + lane];
    float c = (float)(e - s);
    float mean = (c > 0.f) ? acc / c : 0.f;
    for (int o = 0; o < 10; ++o) {
        float t = mean * Wl[lane * 10 + o];
        for (int off = 32; off > 0; off >>= 1) t += __shfl_down(t, off);
        if (lane == 0) out[g * 10 + o] = t + bl[o];
    }
}

extern "C" void kernel_launch(void* const* d_in, const int* in_sizes, int n_in,
                              void* d_out, int out_size, void* d_ws, size_t ws_size,
                              hipStream_t stream) {
    const float* x     = (const float*)d_in[0];
    const int*   ei    = (const int*)d_in[1];
    const int*   batch = (const int*)d_in[2];
    const float* W1    = (const float*)d_in[3];
    const float* W2    = (const float*)d_in[4];
    const float* W3    = (const float*)d_in[5];
    const float* Wl    = (const float*)d_in[6];
    const float* bl    = (const float*)d_in[7];
    float* out = (float*)d_out;

    const int N  = in_sizes[0] / 128;  // 50000 (< 65536)
    const int E  = in_sizes[1] / 2;    // 1250000
    const int NG = out_size / 10;      // 500

    const int* src = ei;
    const int* dst = ei + E;

    const int cb = (E + CHUNK - 1) / CHUNK;  // 306

    // workspace carve-out (256B aligned)
    char* ws = (char*)d_ws;
    size_t off = 0;
    auto alloc = [&](size_t bytes) -> void* {
        void* p = ws + off;
        off += bytes;
        off = (off + 255) & ~(size_t)255;
        return p;
    };
    int*   bucket_cnt  = (int*)alloc((size_t)NBUCK * 4);
    int*   bucket_base = (int*)alloc((size_t)(NBUCK + 1) * 4);
    int*   cursor      = (int*)alloc((size_t)NBUCK * 4);
    unsigned short* csr = (unsigned short*)alloc((size_t)(E + 64) * 2);
    int*   rowptr = (int*)alloc((size_t)(N + 1) * 4);
    float* dinv   = (float*)alloc((size_t)N * 4);
    int*   gptrb  = (int*)alloc((size_t)(NG + 1) * 4);
    unsigned short* GA = (unsigned short*)alloc((size_t)N * CH * 2);  // 6.4MB
    unsigned short* GB = (unsigned short*)alloc((size_t)N * CH * 2);  // 6.4MB
    float* hbuf   = (float*)alloc((size_t)N * CH * 4);   // 12.8MB; aliases pairs (5MB)
    unsigned int* pairs = (unsigned int*)hbuf;  // sort consumes before agg3 writes hbuf

    hipMemsetAsync(bucket_cnt, 0, (size_t)NBUCK * 4, stream);

    int gb = (N + 63) / 64;            // 782 gemm tiles
    int ab = ((N + 7) / 8 + 3) / 4;    // agg: 8 nodes/wave, 4 waves/block

    // K0: gemm1 (raw messages) + histogram chunks in one launch
    gemm1_hist_kernel<128><<<gb + cb, 256, 0, stream>>>(x, W1, GA, N,
                                                        dst, bucket_cnt, E, gb);
    scan_gptr_kernel<<<2, 256, 0, stream>>>(bucket_cnt, bucket_base, cursor,
                                            rowptr, batch, gptrb, N, E, NG);
    bin_kernel<<<cb, 256, 0, stream>>>(src, dst, cursor, pairs, E);
    bucket_sort_kernel<<<NBUCK, 256, 0, stream>>>(pairs, bucket_base, csr, rowptr, dinv, N);

    // layer 1 aggregate (messages NOT prescaled -> multiply dinv[u] per edge)
    aggregate_kernel<false, false><<<ab, 256, 0, stream>>>(GA, rowptr, csr, dinv,
                                                           GB, N, E, 1);
    // layer 2
    gemm_bf16_kernel<<<gb, 256, 0, stream>>>(GB, W2, dinv, GA, N);
    aggregate_kernel<true, false><<<ab, 256, 0, stream>>>(GA, rowptr, csr, dinv,
                                                          GB, N, E, 1);
    // layer 3
    gemm_bf16_kernel<<<gb, 256, 0, stream>>>(GB, W3, dinv, GA, N);
    aggregate_kernel<true, true><<<ab, 256, 0, stream>>>(GA, rowptr, csr, dinv,
                                                         hbuf, N, E, 0);

    // mean pool + linear head
    pool_head_kernel<<<NG, 64, 0, stream>>>(hbuf, gptrb, Wl, bl, out, NG);
}